// Round 1
// baseline (211.447 us; speedup 1.0000x reference)
//
#include <hip/hip_runtime.h>
#include <hip/hip_bf16.h>

// GATConv, N=8192, F_in=F_out=128, dense 0/1 adjacency (int32).
// Rank-1 logits: e_ij = LeakyReLU(es_i + ed_j), es = X@(W@a_src), ed = X@(W@a_dst).
// No max-shift needed (|logit| <~ 9 -> exp safe in f32); partial sums are additive.

typedef __bf16 bf16_t;
typedef bf16_t bf16x8 __attribute__((ext_vector_type(8)));
typedef float  f32x4  __attribute__((ext_vector_type(4)));
typedef int    i32x4  __attribute__((ext_vector_type(4)));

#define NN 8192
#define DD 128

// ---- K0: wsv = W @ a_src, wdv = W @ a_dst (128 threads, 1 block) ----
__global__ void k0_vecs(const float* __restrict__ W, const float* __restrict__ a_src,
                        const float* __restrict__ a_dst, float* __restrict__ wsv,
                        float* __restrict__ wdv) {
  const int k = threadIdx.x;  // 0..127
  float s = 0.f, d = 0.f;
  #pragma unroll
  for (int c = 0; c < DD; ++c) {
    const float w = W[k * DD + c];
    s += w * a_src[c];
    d += w * a_dst[c];
  }
  wsv[k] = s;
  wdv[k] = d;
}

// ---- K_esed: es[i] = X[i,:] . wsv ; ed[i] = X[i,:] . wdv ----
__global__ void k_esed(const float* __restrict__ X, const float* __restrict__ wsv,
                       const float* __restrict__ wdv, float* __restrict__ es,
                       float* __restrict__ ed) {
  const int i = blockIdx.x * 256 + threadIdx.x;  // 8192 threads
  const f32x4* xr = (const f32x4*)(X + (size_t)i * DD);
  const f32x4* av = (const f32x4*)wsv;
  const f32x4* bv = (const f32x4*)wdv;
  float s = 0.f, d = 0.f;
  #pragma unroll
  for (int k = 0; k < 32; ++k) {
    const f32x4 x = xr[k], a = av[k], b = bv[k];
    s += x[0] * a[0] + x[1] * a[1] + x[2] * a[2] + x[3] * a[3];
    d += x[0] * b[0] + x[1] * b[1] + x[2] * b[2] + x[3] * b[3];
  }
  es[i] = s;
  ed[i] = d;
}

// ---- K1: Hb = bf16(X @ W), row-major. 256 blocks x 256 thr, W staged in LDS ----
__global__ __launch_bounds__(256) void k1_proj(const float* __restrict__ X,
                                               const float* __restrict__ W,
                                               bf16_t* __restrict__ Hb) {
  __shared__ float Wl[DD * DD];  // 64 KB
  const int t = threadIdx.x;
  for (int idx = t; idx < DD * DD; idx += 256) Wl[idx] = W[idx];
  __syncthreads();
  const int c = t & 127;
  const int r0 = t >> 7;  // 0/1
  const int rb = blockIdx.x << 5;
  for (int rr = 0; rr < 16; ++rr) {
    const int r = (rr << 1) + r0;
    const f32x4* xrow = (const f32x4*)(X + (size_t)(rb + r) * DD);
    float acc = 0.f;
    #pragma unroll
    for (int k4 = 0; k4 < 32; ++k4) {
      const f32x4 xv = xrow[k4];
      acc += xv[0] * Wl[(k4 * 4 + 0) * DD + c] + xv[1] * Wl[(k4 * 4 + 1) * DD + c] +
             xv[2] * Wl[(k4 * 4 + 2) * DD + c] + xv[3] * Wl[(k4 * 4 + 3) * DD + c];
    }
    Hb[(size_t)(rb + r) * DD + c] = (bf16_t)acc;
  }
}

// ---- K1T: HbT[c][j] = Hb[j][c]  (128 x 8192 bf16) ----
__global__ __launch_bounds__(256) void k1_transpose(const bf16_t* __restrict__ Hb,
                                                    bf16_t* __restrict__ HbT) {
  __shared__ bf16_t tile[64][72];  // padded
  const int jt = blockIdx.x << 6;  // 0..8128
  const int ct = blockIdx.y << 6;  // 0 or 64
  const int t = threadIdx.x;
  for (int idx = t; idx < 4096; idx += 256) {
    const int r = idx >> 6, c = idx & 63;
    tile[r][c] = Hb[(size_t)(jt + r) * DD + ct + c];
  }
  __syncthreads();
  for (int idx = t; idx < 4096; idx += 256) {
    const int c = idx >> 6, r = idx & 63;
    HbT[(size_t)(ct + c) * NN + jt + r] = tile[r][c];
  }
}

// ---- K2: main. 256 WGs x 512 thr. WG owns 32 rows; 8 waves split the j axis. ----
// Per step: lane builds 8 P-values directly in the mfma_16x16x32_bf16 A-frag
// layout (row = lane&15, k = (lane>>4)*8 + t); B-frags = 16B contiguous reads of
// HbT (L2-resident). A streamed nontemporally with 2-step register prefetch.
__global__ __launch_bounds__(512) void k2_gat(const int* __restrict__ A,
                                              const float* __restrict__ es,
                                              const float* __restrict__ ed,
                                              const bf16_t* __restrict__ HbT,
                                              float* __restrict__ out) {
  __shared__ float numLDS[32 * DD];  // 16 KB
  __shared__ float denLDS[32];
  const int t = threadIdx.x;
  for (int idx = t; idx < 32 * DD; idx += 512) numLDS[idx] = 0.f;
  if (t < 32) denLDS[t] = 0.f;
  __syncthreads();

  const int wave = t >> 6;
  const int lane = t & 63;
  const int l16 = lane & 15;
  const int lk = lane >> 4;  // 0..3
  const int rowbase = blockIdx.x << 5;
  const int i0 = rowbase + l16;
  const int i1 = i0 + 16;
  const float esv0 = es[i0];
  const float esv1 = es[i1];
  const int* Arow0 = A + (size_t)i0 * NN;
  const int* Arow1 = A + (size_t)i1 * NN;

  f32x4 acc0[8], acc1[8];
  #pragma unroll
  for (int cf = 0; cf < 8; ++cf) {
    acc0[cf] = f32x4{0.f, 0.f, 0.f, 0.f};
    acc1[cf] = f32x4{0.f, 0.f, 0.f, 0.f};
  }
  float den0 = 0.f, den1 = 0.f;

  auto ldA = [&](int s, i32x4& x00, i32x4& x01, i32x4& x10, i32x4& x11, f32x4& y0,
                 f32x4& y1) {
    const int jj = (((s << 3) + wave) << 5) + (lk << 3);
    x00 = __builtin_nontemporal_load((const i32x4*)(Arow0 + jj));
    x01 = __builtin_nontemporal_load((const i32x4*)(Arow0 + jj + 4));
    x10 = __builtin_nontemporal_load((const i32x4*)(Arow1 + jj));
    x11 = __builtin_nontemporal_load((const i32x4*)(Arow1 + jj + 4));
    y0 = *(const f32x4*)(ed + jj);
    y1 = *(const f32x4*)(ed + jj + 4);
  };

  auto step = [&](int s, i32x4& x00, i32x4& x01, i32x4& x10, i32x4& x11, f32x4& y0,
                  f32x4& y1) {
    const int jbase = ((s << 3) + wave) << 5;
    const int jj = jbase + (lk << 3);
    bf16x8 pa0, pa1;
    float ps0 = 0.f, ps1 = 0.f;
    #pragma unroll
    for (int q = 0; q < 8; ++q) {
      const int av0 = (q < 4) ? x00[q] : x01[q - 4];
      const int av1 = (q < 4) ? x10[q] : x11[q - 4];
      const float edq = (q < 4) ? y0[q] : y1[q - 4];
      const int j = jj + q;
      float e0 = esv0 + edq;
      e0 = e0 > 0.f ? e0 : 0.2f * e0;
      float e1 = esv1 + edq;
      e1 = e1 > 0.f ? e1 : 0.2f * e1;
      const float p0 = (av0 > 0 || j == i0) ? __expf(e0) : 0.f;
      const float p1 = (av1 > 0 || j == i1) ? __expf(e1) : 0.f;
      ps0 += p0;
      ps1 += p1;
      pa0[q] = (bf16_t)p0;
      pa1[q] = (bf16_t)p1;
    }
    den0 += ps0;
    den1 += ps1;
    // prefetch step s+2 into the just-freed buffers (2 deep: ~2 steps of HBM latency)
    if (s + 2 < 32) ldA(s + 2, x00, x01, x10, x11, y0, y1);
    const bf16_t* vbase = HbT + jj;
    #pragma unroll
    for (int cf = 0; cf < 8; ++cf) {
      const bf16x8 vb = *(const bf16x8*)(vbase + (size_t)(cf * 16 + l16) * NN);
      acc0[cf] = __builtin_amdgcn_mfma_f32_16x16x32_bf16(pa0, vb, acc0[cf], 0, 0, 0);
      acc1[cf] = __builtin_amdgcn_mfma_f32_16x16x32_bf16(pa1, vb, acc1[cf], 0, 0, 0);
    }
  };

  i32x4 a00, a01, a10, a11, b00, b01, b10, b11;
  f32x4 ea0, ea1, eb0, eb1;
  ldA(0, a00, a01, a10, a11, ea0, ea1);
  ldA(1, b00, b01, b10, b11, eb0, eb1);
  #pragma unroll 1
  for (int s = 0; s < 32; s += 2) {
    step(s, a00, a01, a10, a11, ea0, ea1);
    step(s + 1, b00, b01, b10, b11, eb0, eb1);
  }

  // cross-wave reduction (sums are additive; order-independent up to fp rounding)
  atomicAdd(&denLDS[l16], den0);
  atomicAdd(&denLDS[16 + l16], den1);
  #pragma unroll
  for (int cf = 0; cf < 8; ++cf) {
    #pragma unroll
    for (int r = 0; r < 4; ++r) {
      const int irow = (lk << 2) + r;  // C/D: row=(lane>>4)*4+reg, col=lane&15
      atomicAdd(&numLDS[irow * DD + cf * 16 + l16], acc0[cf][r]);
      atomicAdd(&numLDS[(16 + irow) * DD + cf * 16 + l16], acc1[cf][r]);
    }
  }
  __syncthreads();

  // epilogue: divide by denom, ELU, write f32 out (coalesced)
  const int row = t >> 4;
  const int c0 = (t & 15) << 3;
  const float rd = 1.f / denLDS[row];
  f32x4 o0, o1;
  #pragma unroll
  for (int q = 0; q < 4; ++q) {
    float v = numLDS[row * DD + c0 + q] * rd;
    o0[q] = v > 0.f ? v : (__expf(v) - 1.f);
    v = numLDS[row * DD + c0 + 4 + q] * rd;
    o1[q] = v > 0.f ? v : (__expf(v) - 1.f);
  }
  float* op = out + (size_t)(rowbase + row) * DD + c0;
  *(f32x4*)op = o0;
  *(f32x4*)(op + 4) = o1;
}

extern "C" void kernel_launch(void* const* d_in, const int* in_sizes, int n_in,
                              void* d_out, int out_size, void* d_ws, size_t ws_size,
                              hipStream_t stream) {
  const float* X = (const float*)d_in[0];
  const int* A = (const int*)d_in[1];
  const float* W = (const float*)d_in[2];
  const float* a_src = (const float*)d_in[3];
  const float* a_dst = (const float*)d_in[4];
  float* out = (float*)d_out;

  char* w = (char*)d_ws;
  float* wsv = (float*)(w + 0);            // 512 B
  float* wdv = (float*)(w + 512);          // 512 B
  float* es = (float*)(w + 1024);          // 32 KB
  float* ed = (float*)(w + 33792);         // 32 KB
  bf16_t* Hb = (bf16_t*)(w + 66560);       // 2 MB
  bf16_t* HbT = (bf16_t*)(w + 2163712);    // 2 MB   (total ~4.1 MB)

  hipLaunchKernelGGL(k0_vecs, dim3(1), dim3(128), 0, stream, W, a_src, a_dst, wsv, wdv);
  hipLaunchKernelGGL(k_esed, dim3(32), dim3(256), 0, stream, X, wsv, wdv, es, ed);
  hipLaunchKernelGGL(k1_proj, dim3(256), dim3(256), 0, stream, X, W, Hb);
  hipLaunchKernelGGL(k1_transpose, dim3(128, 2), dim3(256), 0, stream, Hb, HbT);
  hipLaunchKernelGGL(k2_gat, dim3(256), dim3(512), 0, stream, A, es, ed, HbT, out);
}